// Round 1
// baseline (1238.714 us; speedup 1.0000x reference)
//
#include <hip/hip_runtime.h>
#include <hip/hip_cooperative_groups.h>
#include <stdint.h>
#include <math.h>

namespace cg = cooperative_groups;

static constexpr int NIMG  = 16;
static constexpr int HH    = 512;
static constexpr int WW    = 512;
static constexpr int TOTAL = NIMG * HH * WW;   // 4,194,304
static constexpr int MAXIT = 128;

// workspace layout (bytes)
static constexpr size_t OFF_TMP   = 0;                         // f32 blur temp, TOTAL*4
static constexpr size_t OFF_BUFA  = (size_t)TOTAL * 4;         // u8 ping
static constexpr size_t OFF_BUFB  = OFF_BUFA + TOTAL;          // u8 pong
static constexpr size_t OFF_FLAGS = OFF_BUFB + TOTAL;          // int[128]
static constexpr size_t OFF_ACC   = OFF_FLAGS + MAXIT * 4;     // double[2] (8-aligned)
static constexpr size_t OFF_GK    = OFF_ACC + 2 * 8;           // float[9]

// --- init: zero flags/accumulators, compute gaussian taps exactly like numpy (f64 -> f32)
__global__ void init_kernel(int* flags, double* acc, float* gk) {
    int t = threadIdx.x;
    if (t < MAXIT) flags[t] = 0;
    if (t < 2) acc[t] = 0.0;
    if (t < 9) {
        double s = 0.0;
        for (int i = 0; i < 9; ++i) {
            double x = (double)(i - 4);
            s += exp(-0.5 * x * x);
        }
        double x = (double)(t - 4);
        gk[t] = (float)(exp(-0.5 * x * x) / s);
    }
}

// --- blur along H (axis=1), symmetric padding
__global__ void __launch_bounds__(256) blur_h(const float* __restrict__ in, float* __restrict__ out,
                                              const float* __restrict__ gk) {
    int idx = blockIdx.x * blockDim.x + threadIdx.x;
    if (idx >= TOTAL) return;
    int x = idx & (WW - 1);
    int y = (idx >> 9) & (HH - 1);
    int base = idx - (y << 9) - x;   // image base
    float s = 0.f;
#pragma unroll
    for (int t = 0; t < 9; ++t) {
        int yy = y + t - 4;
        yy = yy < 0 ? -yy - 1 : (yy >= HH ? 2 * HH - 1 - yy : yy);
        s += gk[t] * in[base + (yy << 9) + x];
    }
    out[idx] = s;
}

// --- blur along W (axis=2), symmetric padding, then threshold > 0.1
__global__ void __launch_bounds__(256) blur_w_thresh(const float* __restrict__ in, uint8_t* __restrict__ bin,
                                                     const float* __restrict__ gk) {
    int idx = blockIdx.x * blockDim.x + threadIdx.x;
    if (idx >= TOTAL) return;
    int x = idx & (WW - 1);
    int rowbase = idx - x;
    float s = 0.f;
#pragma unroll
    for (int t = 0; t < 9; ++t) {
        int xx = x + t - 4;
        xx = xx < 0 ? -xx - 1 : (xx >= WW ? 2 * WW - 1 - xx : xx);
        s += gk[t] * in[rowbase + xx];
    }
    bin[idx] = (s > 0.1f) ? (uint8_t)1 : (uint8_t)0;
}

// --- one Zhang-Suen sub-step over the whole batch; returns 1 if this thread deleted anything
__device__ __forceinline__ int zs_substep(const uint8_t* __restrict__ cur, uint8_t* __restrict__ nxt,
                                          int step, int gid, int gsz) {
    int changed = 0;
    for (int idx = gid; idx < TOTAL; idx += gsz) {
        uint8_t c = cur[idx];
        uint8_t o = c;
        if (c) {
            int x = idx & (WW - 1);
            int y = (idx >> 9) & (HH - 1);
            const uint8_t* img = cur + (idx - (y << 9) - x);
            int yo = (y << 9) + x;
            bool xm = x > 0, xp = x < WW - 1, ym = y > 0, yp = y < HH - 1;
            // P2..P9 clockwise from north; zero-padded border
            int p2 = ym          ? img[yo - WW]     : 0;
            int p3 = (ym && xp)  ? img[yo - WW + 1] : 0;
            int p4 = xp          ? img[yo + 1]      : 0;
            int p5 = (yp && xp)  ? img[yo + WW + 1] : 0;
            int p6 = yp          ? img[yo + WW]     : 0;
            int p7 = (yp && xm)  ? img[yo + WW - 1] : 0;
            int p8 = xm          ? img[yo - 1]      : 0;
            int p9 = (ym && xm)  ? img[yo - WW - 1] : 0;
            int Bn = p2 + p3 + p4 + p5 + p6 + p7 + p8 + p9;
            if (Bn >= 2 && Bn <= 6) {
                int A = ((!p2) & p3) + ((!p3) & p4) + ((!p4) & p5) + ((!p5) & p6)
                      + ((!p6) & p7) + ((!p7) & p8) + ((!p8) & p9) + ((!p9) & p2);
                if (A == 1) {
                    bool c1, c2;
                    if (step == 0) { c1 = !(p2 && p4 && p6); c2 = !(p4 && p6 && p8); }
                    else           { c1 = !(p2 && p4 && p8); c2 = !(p2 && p6 && p8); }
                    if (c1 && c2) { o = 0; changed = 1; }
                }
            }
        }
        nxt[idx] = o;
    }
    return changed;
}

// --- cooperative thinning loop; result always ends in bufA (2 swaps per iteration)
__global__ void __launch_bounds__(256) skel_kernel(uint8_t* bufA, uint8_t* bufB, int* flags) {
    cg::grid_group grid = cg::this_grid();
    int gid = blockIdx.x * blockDim.x + threadIdx.x;
    int gsz = gridDim.x * blockDim.x;
    uint8_t* cur = bufA;
    uint8_t* nxt = bufB;
    for (int it = 0; it < MAXIT; ++it) {
        int ch = zs_substep(cur, nxt, 0, gid, gsz);
        if (__any(ch) && (threadIdx.x & 63) == 0) atomicOr(&flags[it], 1);
        grid.sync();
        { uint8_t* t = cur; cur = nxt; nxt = t; }
        ch = zs_substep(cur, nxt, 1, gid, gsz);
        if (__any(ch) && (threadIdx.x & 63) == 0) atomicOr(&flags[it], 1);
        grid.sync();
        { uint8_t* t = cur; cur = nxt; nxt = t; }
        int f = __hip_atomic_load(&flags[it], __ATOMIC_RELAXED, __HIP_MEMORY_SCOPE_AGENT);
        if (!f) break;   // uniform across the grid: all atomicOrs precede the sync
    }
}

// --- fused loss reduction: sum(diff^2) and sum(diff^2 * mask), f64 accumulation
__global__ void __launch_bounds__(256) reduce_kernel(const float* __restrict__ pred, const float* __restrict__ gt,
                                                     const uint8_t* __restrict__ mask, double* acc) {
    __shared__ double sh0[256];
    __shared__ double sh1[256];
    double a0 = 0.0, a1 = 0.0;
    for (int idx = blockIdx.x * blockDim.x + threadIdx.x; idx < TOTAL; idx += gridDim.x * blockDim.x) {
        float d = pred[idx] - gt[idx];
        double d2 = (double)d * (double)d;
        a0 += d2;
        if (mask[idx]) a1 += d2;
    }
    sh0[threadIdx.x] = a0;
    sh1[threadIdx.x] = a1;
    __syncthreads();
    for (int off = 128; off > 0; off >>= 1) {
        if (threadIdx.x < (unsigned)off) {
            sh0[threadIdx.x] += sh0[threadIdx.x + off];
            sh1[threadIdx.x] += sh1[threadIdx.x + off];
        }
        __syncthreads();
    }
    if (threadIdx.x == 0) {
        atomicAdd(&acc[0], sh0[0]);
        atomicAdd(&acc[1], sh1[0]);
    }
}

__global__ void finalize_kernel(const double* acc, float* out) {
    out[0] = (float)(0.5 * (acc[0] + acc[1]) / (double)TOTAL);
}

extern "C" void kernel_launch(void* const* d_in, const int* in_sizes, int n_in,
                              void* d_out, int out_size, void* d_ws, size_t ws_size,
                              hipStream_t stream) {
    const float* pred = (const float*)d_in[0];
    const float* gt   = (const float*)d_in[1];
    char* ws = (char*)d_ws;
    float*   tmp   = (float*)(ws + OFF_TMP);
    uint8_t* bufA  = (uint8_t*)(ws + OFF_BUFA);
    uint8_t* bufB  = (uint8_t*)(ws + OFF_BUFB);
    int*     flags = (int*)(ws + OFF_FLAGS);
    double*  acc   = (double*)(ws + OFF_ACC);
    float*   gk    = (float*)(ws + OFF_GK);

    init_kernel<<<1, 256, 0, stream>>>(flags, acc, gk);

    int nb = (TOTAL + 255) / 256;
    blur_h<<<nb, 256, 0, stream>>>(gt, tmp, gk);
    blur_w_thresh<<<nb, 256, 0, stream>>>(tmp, bufA, gk);

    // cooperative launch: 512 blocks x 256 threads = 2 blocks/CU, safely co-resident
    void* kargs[] = { (void*)&bufA, (void*)&bufB, (void*)&flags };
    hipLaunchCooperativeKernel(reinterpret_cast<void*>(skel_kernel), dim3(512), dim3(256),
                               kargs, 0, stream);

    reduce_kernel<<<4096, 256, 0, stream>>>(pred, gt, bufA, acc);
    finalize_kernel<<<1, 1, 0, stream>>>(acc, (float*)d_out);
}

// Round 2
// 530.220 us; speedup vs baseline: 2.3362x; 2.3362x over previous
//
#include <hip/hip_runtime.h>
#include <hip/hip_cooperative_groups.h>
#include <stdint.h>
#include <math.h>

namespace cg = cooperative_groups;

static constexpr int NIMG  = 16;
static constexpr int HH    = 512;
static constexpr int WW    = 512;
static constexpr int TOTAL = NIMG * HH * WW;   // 4,194,304 pixels
static constexpr int WPR   = WW / 64;          // 8 qwords per row
static constexpr int NQ    = TOTAL / 64;       // 65,536 qwords
static constexpr int MAXIT = 128;

// workspace layout (bytes)
static constexpr size_t OFF_TMP   = 0;                          // f32 blur temp, TOTAL*4
static constexpr size_t OFF_PA    = (size_t)TOTAL * 4;          // packed ping, NQ*8
static constexpr size_t OFF_PB    = OFF_PA + (size_t)NQ * 8;    // packed pong
static constexpr size_t OFF_FLAGS = OFF_PB + (size_t)NQ * 8;    // int[128]
static constexpr size_t OFF_ACC   = OFF_FLAGS + MAXIT * 4;      // double[2] (8-aligned)
static constexpr size_t OFF_GK    = OFF_ACC + 2 * 8;            // float[9]

__global__ void init_kernel(int* flags, double* acc, float* gk) {
    int t = threadIdx.x;
    if (t < MAXIT) flags[t] = 0;
    if (t < 2) acc[t] = 0.0;
    if (t < 9) {
        double s = 0.0;
        for (int i = 0; i < 9; ++i) {
            double x = (double)(i - 4);
            s += exp(-0.5 * x * x);
        }
        double x = (double)(t - 4);
        gk[t] = (float)(exp(-0.5 * x * x) / s);
    }
}

// --- blur along H (axis=1), symmetric padding
__global__ void __launch_bounds__(256) blur_h(const float* __restrict__ in, float* __restrict__ out,
                                              const float* __restrict__ gk) {
    int idx = blockIdx.x * blockDim.x + threadIdx.x;
    if (idx >= TOTAL) return;
    int x = idx & (WW - 1);
    int y = (idx >> 9) & (HH - 1);
    int base = idx - (y << 9) - x;
    float s = 0.f;
#pragma unroll
    for (int t = 0; t < 9; ++t) {
        int yy = y + t - 4;
        yy = yy < 0 ? -yy - 1 : (yy >= HH ? 2 * HH - 1 - yy : yy);
        s += gk[t] * in[base + (yy << 9) + x];
    }
    out[idx] = s;
}

// --- blur along W (axis=2), symmetric padding, threshold > 0.1, pack 1 bit/pixel via ballot
__global__ void __launch_bounds__(256) blur_w_pack(const float* __restrict__ in, uint64_t* __restrict__ packed,
                                                   const float* __restrict__ gk) {
    int idx = blockIdx.x * blockDim.x + threadIdx.x;
    int x = idx & (WW - 1);
    int rowbase = idx - x;
    float s = 0.f;
#pragma unroll
    for (int t = 0; t < 9; ++t) {
        int xx = x + t - 4;
        xx = xx < 0 ? -xx - 1 : (xx >= WW ? 2 * WW - 1 - xx : xx);
        s += gk[t] * in[rowbase + xx];
    }
    uint64_t m = __ballot(s > 0.1f);
    if ((threadIdx.x & 63) == 0) packed[idx >> 6] = m;
}

// full adder on 64 bit-lanes
__device__ __forceinline__ void fa(uint64_t a, uint64_t b, uint64_t c, uint64_t& s, uint64_t& cy) {
    uint64_t axb = a ^ b;
    s  = axb ^ c;
    cy = (a & b) | (c & axb);
}

// --- one bit-sliced Zhang-Suen sub-step; thread owns one 64-pixel qword
__device__ __forceinline__ int zs_substep_bits(const uint64_t* __restrict__ cur, uint64_t* __restrict__ nxt,
                                               int step, int q) {
    int wx = q & (WPR - 1);
    int y  = (q >> 3) & (HH - 1);
    bool yn = y > 0, ys = y < HH - 1;
    bool xw = wx > 0, xe = wx < WPR - 1;

    uint64_t cc = cur[q];
    uint64_t cw = xw ? cur[q - 1] : 0;
    uint64_t ce = xe ? cur[q + 1] : 0;
    uint64_t nc = yn ? cur[q - WPR] : 0;
    uint64_t nw = (yn && xw) ? cur[q - WPR - 1] : 0;
    uint64_t ne = (yn && xe) ? cur[q - WPR + 1] : 0;
    uint64_t sc = ys ? cur[q + WPR] : 0;
    uint64_t sw = (ys && xw) ? cur[q + WPR - 1] : 0;
    uint64_t se = (ys && xe) ? cur[q + WPR + 1] : 0;

    // neighbor maps: bit j of result = neighbor value of pixel j
    // east (x+1): src >> 1, MSB from next word's LSB;  west (x-1): src << 1, LSB from prev word's MSB
    uint64_t p2 = nc;
    uint64_t p3 = (nc >> 1) | (ne << 63);
    uint64_t p4 = (cc >> 1) | (ce << 63);
    uint64_t p5 = (sc >> 1) | (se << 63);
    uint64_t p6 = sc;
    uint64_t p7 = (sc << 1) | (sw >> 63);
    uint64_t p8 = (cc << 1) | (cw >> 63);
    uint64_t p9 = (nc << 1) | (nw >> 63);

    // Bn = p2+...+p9 as 4 bit-planes
    uint64_t s1, k1, s2, k2;
    fa(p2, p3, p4, s1, k1);
    fa(p5, p6, p7, s2, k2);
    uint64_t s3 = p8 ^ p9, k3 = p8 & p9;
    uint64_t b0, k4;
    fa(s1, s2, s3, b0, k4);
    uint64_t t1, t2;
    fa(k1, k2, k3, t1, t2);         // t1 w2, t2 w4
    uint64_t b1 = t1 ^ k4;
    uint64_t k5 = t1 & k4;          // w4
    uint64_t b2 = t2 ^ k5;
    uint64_t b3 = t2 & k5;          // w8
    uint64_t ge2 = b1 | b2 | b3;
    uint64_t le6 = ~(b3 | (b0 & b1 & b2));
    uint64_t condB = ge2 & le6;

    // A = number of 0->1 transitions in p2,p3,...,p9,p2 ; need A == 1
    uint64_t q0 = ~p2 & p3, q1 = ~p3 & p4, q2 = ~p4 & p5, q3 = ~p5 & p6;
    uint64_t q4 = ~p6 & p7, q5 = ~p7 & p8, q6 = ~p8 & p9, q7 = ~p9 & p2;
    uint64_t u1, v1, u2, v2;
    fa(q0, q1, q2, u1, v1);
    fa(q3, q4, q5, u2, v2);
    uint64_t u3 = q6 ^ q7, v3 = q6 & q7;
    uint64_t a0, v4;
    fa(u1, u2, u3, a0, v4);
    uint64_t w1, w2;
    fa(v1, v2, v3, w1, w2);         // w1 w2(eight-weight-2), w2 w4
    uint64_t a1 = w1 ^ v4;
    uint64_t ka = w1 & v4;
    uint64_t a2 = w2 ^ ka;
    uint64_t a3 = w2 & ka;
    uint64_t condA = a0 & ~a1 & ~a2 & ~a3;

    uint64_t nc1, nc2;
    if (step == 0) { nc1 = ~(p2 & p4 & p6); nc2 = ~(p4 & p6 & p8); }
    else           { nc1 = ~(p2 & p4 & p8); nc2 = ~(p2 & p6 & p8); }

    uint64_t del = cc & condB & condA & nc1 & nc2;
    nxt[q] = cc & ~del;
    return del != 0;
}

// --- cooperative thinning loop on packed bitmaps; result always ends in bufA
__global__ void __launch_bounds__(256) skel_kernel(uint64_t* bufA, uint64_t* bufB, int* flags) {
    cg::grid_group grid = cg::this_grid();
    int q = blockIdx.x * blockDim.x + threadIdx.x;   // one qword per thread, grid == NQ
    uint64_t* cur = bufA;
    uint64_t* nxt = bufB;
    for (int it = 0; it < MAXIT; ++it) {
        int ch = zs_substep_bits(cur, nxt, 0, q);
        if (__any(ch) && (threadIdx.x & 63) == 0) atomicOr(&flags[it], 1);
        grid.sync();
        { uint64_t* t = cur; cur = nxt; nxt = t; }
        ch = zs_substep_bits(cur, nxt, 1, q);
        if (__any(ch) && (threadIdx.x & 63) == 0) atomicOr(&flags[it], 1);
        grid.sync();
        { uint64_t* t = cur; cur = nxt; nxt = t; }
        int f = __hip_atomic_load(&flags[it], __ATOMIC_RELAXED, __HIP_MEMORY_SCOPE_AGENT);
        if (!f) break;   // uniform: all atomicOrs happened before the sync
    }
}

// --- fused loss reduction: sum(diff^2) and sum(diff^2 * mask), f64 accumulation
__global__ void __launch_bounds__(256) reduce_kernel(const float* __restrict__ pred, const float* __restrict__ gt,
                                                     const uint64_t* __restrict__ mask, double* acc) {
    __shared__ double sh0[256];
    __shared__ double sh1[256];
    double a0 = 0.0, a1 = 0.0;
    for (int idx = blockIdx.x * blockDim.x + threadIdx.x; idx < TOTAL; idx += gridDim.x * blockDim.x) {
        float d = pred[idx] - gt[idx];
        double d2 = (double)d * (double)d;
        a0 += d2;
        if ((mask[idx >> 6] >> (idx & 63)) & 1) a1 += d2;
    }
    sh0[threadIdx.x] = a0;
    sh1[threadIdx.x] = a1;
    __syncthreads();
    for (int off = 128; off > 0; off >>= 1) {
        if (threadIdx.x < (unsigned)off) {
            sh0[threadIdx.x] += sh0[threadIdx.x + off];
            sh1[threadIdx.x] += sh1[threadIdx.x + off];
        }
        __syncthreads();
    }
    if (threadIdx.x == 0) {
        atomicAdd(&acc[0], sh0[0]);
        atomicAdd(&acc[1], sh1[0]);
    }
}

__global__ void finalize_kernel(const double* acc, float* out) {
    out[0] = (float)(0.5 * (acc[0] + acc[1]) / (double)TOTAL);
}

extern "C" void kernel_launch(void* const* d_in, const int* in_sizes, int n_in,
                              void* d_out, int out_size, void* d_ws, size_t ws_size,
                              hipStream_t stream) {
    const float* pred = (const float*)d_in[0];
    const float* gt   = (const float*)d_in[1];
    char* ws = (char*)d_ws;
    float*    tmp   = (float*)(ws + OFF_TMP);
    uint64_t* bufA  = (uint64_t*)(ws + OFF_PA);
    uint64_t* bufB  = (uint64_t*)(ws + OFF_PB);
    int*      flags = (int*)(ws + OFF_FLAGS);
    double*   acc   = (double*)(ws + OFF_ACC);
    float*    gk    = (float*)(ws + OFF_GK);

    init_kernel<<<1, 256, 0, stream>>>(flags, acc, gk);

    int nb = TOTAL / 256;
    blur_h<<<nb, 256, 0, stream>>>(gt, tmp, gk);
    blur_w_pack<<<nb, 256, 0, stream>>>(tmp, bufA, gk);

    // cooperative launch: 256 blocks x 256 threads = 65536 threads = one qword each
    void* kargs[] = { (void*)&bufA, (void*)&bufB, (void*)&flags };
    hipLaunchCooperativeKernel(reinterpret_cast<void*>(skel_kernel), dim3(NQ / 256), dim3(256),
                               kargs, 0, stream);

    reduce_kernel<<<2048, 256, 0, stream>>>(pred, gt, bufA, acc);
    finalize_kernel<<<1, 1, 0, stream>>>(acc, (float*)d_out);
}

// Round 3
// 206.047 us; speedup vs baseline: 6.0118x; 2.5733x over previous
//
#include <hip/hip_runtime.h>
#include <stdint.h>
#include <math.h>

static constexpr int NIMG  = 16;
static constexpr int HH    = 512;
static constexpr int WW    = 512;
static constexpr int TOTAL = NIMG * HH * WW;   // 4,194,304 pixels
static constexpr int WPR   = WW / 64;          // 8 qwords per row
static constexpr int QPI   = HH * WPR;         // 4096 qwords per image
static constexpr int NQ    = TOTAL / 64;       // 65,536 qwords
static constexpr int MAXIT = 128;

// workspace layout (bytes)
static constexpr size_t OFF_TMP   = 0;                          // f32 blur temp, TOTAL*4
static constexpr size_t OFF_PA    = (size_t)TOTAL * 4;          // packed bitmap, NQ*8
static constexpr size_t OFF_FLAGS = OFF_PA + (size_t)NQ * 8;    // int[NIMG*MAXIT]
static constexpr size_t OFF_ACC   = OFF_FLAGS + (size_t)NIMG * MAXIT * 4; // double[2]
static constexpr size_t OFF_GK    = OFF_ACC + 2 * 8;            // float[9]

// --- init: zero flags/accumulators, compute gaussian taps exactly like numpy (f64 -> f32)
__global__ void __launch_bounds__(256) init_kernel(int* flags, double* acc, float* gk) {
    int t = threadIdx.x;
    for (int i = t; i < NIMG * MAXIT; i += 256) flags[i] = 0;
    if (t < 2) acc[t] = 0.0;
    if (t < 9) {
        double s = 0.0;
        for (int i = 0; i < 9; ++i) {
            double x = (double)(i - 4);
            s += exp(-0.5 * x * x);
        }
        double x = (double)(t - 4);
        gk[t] = (float)(exp(-0.5 * x * x) / s);
    }
}

// --- blur along H (axis=1), symmetric padding
__global__ void __launch_bounds__(256) blur_h(const float* __restrict__ in, float* __restrict__ out,
                                              const float* __restrict__ gk) {
    int idx = blockIdx.x * blockDim.x + threadIdx.x;
    if (idx >= TOTAL) return;
    int x = idx & (WW - 1);
    int y = (idx >> 9) & (HH - 1);
    int base = idx - (y << 9) - x;
    float s = 0.f;
#pragma unroll
    for (int t = 0; t < 9; ++t) {
        int yy = y + t - 4;
        yy = yy < 0 ? -yy - 1 : (yy >= HH ? 2 * HH - 1 - yy : yy);
        s += gk[t] * in[base + (yy << 9) + x];
    }
    out[idx] = s;
}

// --- blur along W (axis=2), symmetric padding, threshold > 0.1, pack 1 bit/pixel via ballot
__global__ void __launch_bounds__(256) blur_w_pack(const float* __restrict__ in, uint64_t* __restrict__ packed,
                                                   const float* __restrict__ gk) {
    int idx = blockIdx.x * blockDim.x + threadIdx.x;
    int x = idx & (WW - 1);
    int rowbase = idx - x;
    float s = 0.f;
#pragma unroll
    for (int t = 0; t < 9; ++t) {
        int xx = x + t - 4;
        xx = xx < 0 ? -xx - 1 : (xx >= WW ? 2 * WW - 1 - xx : xx);
        s += gk[t] * in[rowbase + xx];
    }
    uint64_t m = __ballot(s > 0.1f);
    if ((threadIdx.x & 63) == 0) packed[idx >> 6] = m;
}

// full adder on 64 bit-lanes
__device__ __forceinline__ void fa(uint64_t a, uint64_t b, uint64_t c, uint64_t& s, uint64_t& cy) {
    uint64_t axb = a ^ b;
    s  = axb ^ c;
    cy = (a & b) | (c & axb);
}

// --- one bit-sliced Zhang-Suen sub-step over one image held in LDS
__device__ __forceinline__ int zs_sub(const uint64_t* __restrict__ cur, uint64_t* __restrict__ nxt, int step) {
    int ch = 0;
    for (int q = threadIdx.x; q < QPI; q += 1024) {
        uint64_t cc = cur[q];
        if (!cc) { nxt[q] = 0; continue; }   // del ⊆ cc, so output is 0 and nothing deleted
        int wx = q & (WPR - 1);
        int y  = q >> 3;
        bool yn = y > 0, ys = y < HH - 1;
        bool xw = wx > 0, xe = wx < WPR - 1;

        uint64_t cw = xw ? cur[q - 1] : 0;
        uint64_t ce = xe ? cur[q + 1] : 0;
        uint64_t nc = yn ? cur[q - WPR] : 0;
        uint64_t nw = (yn && xw) ? cur[q - WPR - 1] : 0;
        uint64_t ne = (yn && xe) ? cur[q - WPR + 1] : 0;
        uint64_t sc = ys ? cur[q + WPR] : 0;
        uint64_t sw = (ys && xw) ? cur[q + WPR - 1] : 0;
        uint64_t se = (ys && xe) ? cur[q + WPR + 1] : 0;

        // neighbor maps: bit j = neighbor value of pixel j (zero-padded border)
        uint64_t p2 = nc;
        uint64_t p3 = (nc >> 1) | (ne << 63);
        uint64_t p4 = (cc >> 1) | (ce << 63);
        uint64_t p5 = (sc >> 1) | (se << 63);
        uint64_t p6 = sc;
        uint64_t p7 = (sc << 1) | (sw >> 63);
        uint64_t p8 = (cc << 1) | (cw >> 63);
        uint64_t p9 = (nc << 1) | (nw >> 63);

        // Bn = p2+...+p9 as 4 bit-planes
        uint64_t s1, k1, s2, k2;
        fa(p2, p3, p4, s1, k1);
        fa(p5, p6, p7, s2, k2);
        uint64_t s3 = p8 ^ p9, k3 = p8 & p9;
        uint64_t b0, k4;
        fa(s1, s2, s3, b0, k4);
        uint64_t t1, t2;
        fa(k1, k2, k3, t1, t2);
        uint64_t b1 = t1 ^ k4;
        uint64_t k5 = t1 & k4;
        uint64_t b2 = t2 ^ k5;
        uint64_t b3 = t2 & k5;
        uint64_t ge2 = b1 | b2 | b3;
        uint64_t le6 = ~(b3 | (b0 & b1 & b2));
        uint64_t condB = ge2 & le6;

        // A == 1: exactly one 0->1 transition around the ring
        uint64_t q0 = ~p2 & p3, q1 = ~p3 & p4, q2 = ~p4 & p5, q3 = ~p5 & p6;
        uint64_t q4 = ~p6 & p7, q5 = ~p7 & p8, q6 = ~p8 & p9, q7 = ~p9 & p2;
        uint64_t u1, v1, u2, v2;
        fa(q0, q1, q2, u1, v1);
        fa(q3, q4, q5, u2, v2);
        uint64_t u3 = q6 ^ q7, v3 = q6 & q7;
        uint64_t a0, v4;
        fa(u1, u2, u3, a0, v4);
        uint64_t w1, w2;
        fa(v1, v2, v3, w1, w2);
        uint64_t a1 = w1 ^ v4;
        uint64_t ka = w1 & v4;
        uint64_t a2 = w2 ^ ka;
        uint64_t a3 = w2 & ka;
        uint64_t condA = a0 & ~a1 & ~a2 & ~a3;

        uint64_t nc1, nc2;
        if (step == 0) { nc1 = ~(p2 & p4 & p6); nc2 = ~(p4 & p6 & p8); }
        else           { nc1 = ~(p2 & p4 & p8); nc2 = ~(p2 & p6 & p8); }

        uint64_t del = cc & condB & condA & nc1 & nc2;
        nxt[q] = cc & ~del;
        ch |= (del != 0);
    }
    return ch;
}

// --- one workgroup per image; whole thinning loop in LDS, no grid sync.
// Per-image convergence is exact: substeps only delete and are identity at the fixed point.
__global__ void __launch_bounds__(1024) skel_kernel(uint64_t* __restrict__ g, int* __restrict__ flags) {
    __shared__ uint64_t SA[QPI];   // 32 KB
    __shared__ uint64_t SB[QPI];   // 32 KB
    const int img = blockIdx.x;
    uint64_t* gimg = g + (size_t)img * QPI;
    int* f = flags + img * MAXIT;
    for (int i = threadIdx.x; i < QPI; i += 1024) SA[i] = gimg[i];
    __syncthreads();
    for (int it = 0; it < MAXIT; ++it) {
        int ch = zs_sub(SA, SB, 0);          // A -> B
        __syncthreads();
        ch |= zs_sub(SB, SA, 1);             // B -> A  (result always ends in A)
        if (ch && (threadIdx.x & 63) == 0) atomicOr(&f[it], 1);
        __syncthreads();                     // drains vmcnt: atomicOr globally visible
        if (!__hip_atomic_load(&f[it], __ATOMIC_RELAXED, __HIP_MEMORY_SCOPE_AGENT))
            break;                           // uniform across block
    }
    for (int i = threadIdx.x; i < QPI; i += 1024) gimg[i] = SA[i];
}

// --- fused loss reduction: sum(diff^2) and sum(diff^2 * mask), f64 accumulation
__global__ void __launch_bounds__(256) reduce_kernel(const float* __restrict__ pred, const float* __restrict__ gt,
                                                     const uint64_t* __restrict__ mask, double* acc) {
    __shared__ double sh0[256];
    __shared__ double sh1[256];
    double a0 = 0.0, a1 = 0.0;
    for (int idx = blockIdx.x * blockDim.x + threadIdx.x; idx < TOTAL; idx += gridDim.x * blockDim.x) {
        float d = pred[idx] - gt[idx];
        double d2 = (double)d * (double)d;
        a0 += d2;
        if ((mask[idx >> 6] >> (idx & 63)) & 1) a1 += d2;
    }
    sh0[threadIdx.x] = a0;
    sh1[threadIdx.x] = a1;
    __syncthreads();
    for (int off = 128; off > 0; off >>= 1) {
        if (threadIdx.x < (unsigned)off) {
            sh0[threadIdx.x] += sh0[threadIdx.x + off];
            sh1[threadIdx.x] += sh1[threadIdx.x + off];
        }
        __syncthreads();
    }
    if (threadIdx.x == 0) {
        atomicAdd(&acc[0], sh0[0]);
        atomicAdd(&acc[1], sh1[0]);
    }
}

__global__ void finalize_kernel(const double* acc, float* out) {
    out[0] = (float)(0.5 * (acc[0] + acc[1]) / (double)TOTAL);
}

extern "C" void kernel_launch(void* const* d_in, const int* in_sizes, int n_in,
                              void* d_out, int out_size, void* d_ws, size_t ws_size,
                              hipStream_t stream) {
    const float* pred = (const float*)d_in[0];
    const float* gt   = (const float*)d_in[1];
    char* ws = (char*)d_ws;
    float*    tmp   = (float*)(ws + OFF_TMP);
    uint64_t* bufA  = (uint64_t*)(ws + OFF_PA);
    int*      flags = (int*)(ws + OFF_FLAGS);
    double*   acc   = (double*)(ws + OFF_ACC);
    float*    gk    = (float*)(ws + OFF_GK);

    init_kernel<<<1, 256, 0, stream>>>(flags, acc, gk);

    int nb = TOTAL / 256;
    blur_h<<<nb, 256, 0, stream>>>(gt, tmp, gk);
    blur_w_pack<<<nb, 256, 0, stream>>>(tmp, bufA, gk);

    skel_kernel<<<NIMG, 1024, 0, stream>>>(bufA, flags);

    reduce_kernel<<<2048, 256, 0, stream>>>(pred, gt, bufA, acc);
    finalize_kernel<<<1, 1, 0, stream>>>(acc, (float*)d_out);
}

// Round 4
// 176.416 us; speedup vs baseline: 7.0215x; 1.1680x over previous
//
#include <hip/hip_runtime.h>
#include <stdint.h>
#include <math.h>

static constexpr int NIMG  = 16;
static constexpr int HH    = 512;
static constexpr int WW    = 512;
static constexpr int TOTAL = NIMG * HH * WW;   // 4,194,304 pixels
static constexpr int WPR   = WW / 64;          // 8 qwords per row
static constexpr int QPI   = HH * WPR;         // 4096 qwords per image
static constexpr int NQ    = TOTAL / 64;       // 65,536 qwords
static constexpr int MAXIT = 128;

static constexpr int S     = 8;                // strips per image
static constexpr int RPS   = HH / S;           // 64 rows per strip
static constexpr int QPS   = RPS * WPR;        // 512 qwords per strip
static constexpr int LROWS = RPS + 2;          // strip + 2 halo rows in LDS
static constexpr int RBLK  = 2048;             // reduce blocks

// workspace layout (bytes)
static constexpr size_t OFF_TMP  = 0;                                  // f32 blur temp
static constexpr size_t OFF_PA   = (size_t)TOTAL * 4;                  // packed bitmap
static constexpr size_t OFF_FLAG = OFF_PA   + (size_t)NQ * 8;          // int[NIMG][MAXIT]
static constexpr size_t OFF_DONE = OFF_FLAG + (size_t)NIMG * MAXIT * 4;
static constexpr size_t OFF_CONV = OFF_DONE + (size_t)NIMG * MAXIT * 4; // int[NIMG]
static constexpr size_t OFF_PSEQ = OFF_CONV + (size_t)NIMG * 4;         // int[NIMG*S]
static constexpr size_t OFF_HALT = OFF_PSEQ + (size_t)NIMG * S * 4;     // u64[NIMG*S*2*WPR]
static constexpr size_t OFF_HALB = OFF_HALT + (size_t)NIMG * S * 2 * WPR * 8;
static constexpr size_t OFF_PART = OFF_HALB + (size_t)NIMG * S * 2 * WPR * 8; // double[RBLK*2]
static constexpr int CTRL_INTS = NIMG * MAXIT * 2 + NIMG + NIMG * S;   // flag+done+conv+pseq (contiguous)

#define LD_ACQ(p)   __hip_atomic_load((p), __ATOMIC_ACQUIRE, __HIP_MEMORY_SCOPE_AGENT)
#define LD_RLX(p)   __hip_atomic_load((p), __ATOMIC_RELAXED, __HIP_MEMORY_SCOPE_AGENT)
#define ST_REL(p,v) __hip_atomic_store((p), (v), __ATOMIC_RELEASE, __HIP_MEMORY_SCOPE_AGENT)
#define ST_RLX(p,v) __hip_atomic_store((p), (v), __ATOMIC_RELAXED, __HIP_MEMORY_SCOPE_AGENT)

// compute gaussian taps exactly like numpy (f64 exp, /sum, cast f32)
__device__ __forceinline__ void make_gk(float* gks) {
    if (threadIdx.x < 9) {
        double ssum = 0.0;
        for (int i = 0; i < 9; ++i) { double x = (double)(i - 4); ssum += exp(-0.5 * x * x); }
        double x = (double)((int)threadIdx.x - 4);
        gks[threadIdx.x] = (float)(exp(-0.5 * x * x) / ssum);
    }
}

// --- blur along H (axis=1), symmetric padding; block 0 also zeroes the skel control area
__global__ void __launch_bounds__(256) blur_h(const float* __restrict__ in, float* __restrict__ out,
                                              int* __restrict__ ctrl) {
    __shared__ float gks[9];
    make_gk(gks);
    if (blockIdx.x == 0) {
        for (int i = threadIdx.x; i < CTRL_INTS; i += 256) ctrl[i] = 0;
    }
    __syncthreads();
    int idx = blockIdx.x * blockDim.x + threadIdx.x;
    int x = idx & (WW - 1);
    int y = (idx >> 9) & (HH - 1);
    int base = idx - (y << 9) - x;
    float s = 0.f;
#pragma unroll
    for (int t = 0; t < 9; ++t) {
        int yy = y + t - 4;
        yy = yy < 0 ? -yy - 1 : (yy >= HH ? 2 * HH - 1 - yy : yy);
        s += gks[t] * in[base + (yy << 9) + x];
    }
    out[idx] = s;
}

// --- blur along W (axis=2), symmetric padding, threshold > 0.1, pack 1 bit/pixel via ballot
__global__ void __launch_bounds__(256) blur_w_pack(const float* __restrict__ in, uint64_t* __restrict__ packed) {
    __shared__ float gks[9];
    make_gk(gks);
    __syncthreads();
    int idx = blockIdx.x * blockDim.x + threadIdx.x;
    int x = idx & (WW - 1);
    int rowbase = idx - x;
    float s = 0.f;
#pragma unroll
    for (int t = 0; t < 9; ++t) {
        int xx = x + t - 4;
        xx = xx < 0 ? -xx - 1 : (xx >= WW ? 2 * WW - 1 - xx : xx);
        s += gks[t] * in[rowbase + xx];
    }
    uint64_t m = __ballot(s > 0.1f);
    if ((threadIdx.x & 63) == 0) packed[idx >> 6] = m;
}

// full adder on 64 bit-lanes
__device__ __forceinline__ void fa(uint64_t a, uint64_t b, uint64_t c, uint64_t& s, uint64_t& cy) {
    uint64_t axb = a ^ b;
    s  = axb ^ c;
    cy = (a & b) | (c & axb);
}

// bit-sliced Zhang-Suen delete mask for one qword given its 8 neighbor qwords (already shifted rows)
__device__ __forceinline__ uint64_t zs_del(uint64_t cc, uint64_t nc, uint64_t sc, uint64_t cw, uint64_t ce,
                                           uint64_t nw, uint64_t ne, uint64_t sw, uint64_t se, int step) {
    uint64_t p2 = nc;
    uint64_t p3 = (nc >> 1) | (ne << 63);
    uint64_t p4 = (cc >> 1) | (ce << 63);
    uint64_t p5 = (sc >> 1) | (se << 63);
    uint64_t p6 = sc;
    uint64_t p7 = (sc << 1) | (sw >> 63);
    uint64_t p8 = (cc << 1) | (cw >> 63);
    uint64_t p9 = (nc << 1) | (nw >> 63);

    uint64_t s1, k1, s2, k2;
    fa(p2, p3, p4, s1, k1);
    fa(p5, p6, p7, s2, k2);
    uint64_t s3 = p8 ^ p9, k3 = p8 & p9;
    uint64_t b0, k4;
    fa(s1, s2, s3, b0, k4);
    uint64_t t1, t2;
    fa(k1, k2, k3, t1, t2);
    uint64_t b1 = t1 ^ k4;
    uint64_t k5 = t1 & k4;
    uint64_t b2 = t2 ^ k5;
    uint64_t b3 = t2 & k5;
    uint64_t ge2 = b1 | b2 | b3;
    uint64_t le6 = ~(b3 | (b0 & b1 & b2));
    uint64_t condB = ge2 & le6;

    uint64_t q0 = ~p2 & p3, q1 = ~p3 & p4, q2 = ~p4 & p5, q3 = ~p5 & p6;
    uint64_t q4 = ~p6 & p7, q5 = ~p7 & p8, q6 = ~p8 & p9, q7 = ~p9 & p2;
    uint64_t u1, v1, u2, v2;
    fa(q0, q1, q2, u1, v1);
    fa(q3, q4, q5, u2, v2);
    uint64_t u3 = q6 ^ q7, v3 = q6 & q7;
    uint64_t a0, v4;
    fa(u1, u2, u3, a0, v4);
    uint64_t w1, w2;
    fa(v1, v2, v3, w1, w2);
    uint64_t a1 = w1 ^ v4;
    uint64_t ka = w1 & v4;
    uint64_t a2 = w2 ^ ka;
    uint64_t a3 = w2 & ka;
    uint64_t condA = a0 & ~a1 & ~a2 & ~a3;

    uint64_t nc1, nc2;
    if (step == 0) { nc1 = ~(p2 & p4 & p6); nc2 = ~(p4 & p6 & p8); }
    else           { nc1 = ~(p2 & p4 & p8); nc2 = ~(p2 & p6 & p8); }

    return cc & condB & condA & nc1 & nc2;
}

// --- strip-parallel thinning: block = (img, strip). Strip + 2 halo rows in LDS ping-pong.
// Halos exchanged p2p through global with per-strip seq flags (parity-double-buffered slots).
__global__ void __launch_bounds__(256) skel_strips(uint64_t* __restrict__ g,
                                                   int* __restrict__ flag, int* __restrict__ done,
                                                   int* __restrict__ conv, int* __restrict__ pubseq,
                                                   uint64_t* __restrict__ haloT, uint64_t* __restrict__ haloB) {
    __shared__ uint64_t SA[LROWS * WPR];
    __shared__ uint64_t SB[LROWS * WPR];
    __shared__ int chflag, exitflag;

    const int tid = threadIdx.x;
    const int img = blockIdx.x / S;
    const int s   = blockIdx.x % S;
    const int myT = blockIdx.x;
    uint64_t* gimg = g + (size_t)img * QPI;

    // load strip + initial halos (state seq 0 straight from the bitmap)
    for (int i = tid; i < QPS; i += 256) SA[WPR + i] = gimg[s * QPS + i];
    if (tid < WPR) {
        SA[tid] = (s > 0) ? gimg[s * QPS - WPR + tid] : 0;
        SB[tid] = 0;
        SA[(LROWS - 1) * WPR + tid] = (s < S - 1) ? gimg[(s + 1) * QPS + tid] : 0;
        SB[(LROWS - 1) * WPR + tid] = 0;
    }
    if (tid == 0) { chflag = 0; exitflag = 0; }
    __syncthreads();

    uint64_t* cur = SA;
    uint64_t* nxt = SB;

    for (int it = 0; it < MAXIT; ++it) {
        for (int sub = 0; sub < 2; ++sub) {
            int seq = 2 * it + sub;          // seq of the input state
            if (seq > 0) {
                // wait for neighbors' state `seq`, with escape if image already converged
                if (tid == 0 && s > 0) {
                    while (LD_ACQ(&pubseq[myT - 1]) < seq) {
                        if (LD_RLX(&conv[img])) { exitflag = 1; break; }
                    }
                }
                if (tid == 1 && s < S - 1) {
                    while (LD_ACQ(&pubseq[myT + 1]) < seq) {
                        if (LD_RLX(&conv[img])) { exitflag = 1; break; }
                    }
                }
                __syncthreads();
                if (exitflag) goto finish;   // current `cur` state == converged state
                int par = seq & 1;
                if (s > 0 && tid < WPR)
                    cur[tid] = LD_RLX(&haloB[(((myT - 1) << 1) | par) * WPR + tid]);
                if (s < S - 1 && tid >= WPR && tid < 2 * WPR)
                    cur[(LROWS - 1) * WPR + (tid - WPR)] = LD_RLX(&haloT[(((myT + 1) << 1) | par) * WPR + (tid - WPR)]);
                __syncthreads();
            }

            // compute sub-step: rows 1..RPS of cur -> nxt
            int ch = 0;
            uint64_t nq0 = 0, nq1 = 0;
#pragma unroll
            for (int k = 0; k < 2; ++k) {
                int q  = tid + k * 256;            // [0, QPS)
                int lr = (q >> 3) + 1;
                int wx = q & 7;
                int base = lr * WPR + wx;
                uint64_t cc = cur[base];
                uint64_t out = 0;
                if (cc) {
                    bool xw = wx > 0, xe = wx < WPR - 1;
                    uint64_t cw  = xw ? cur[base - 1] : 0;
                    uint64_t ce  = xe ? cur[base + 1] : 0;
                    uint64_t nc  = cur[base - WPR];
                    uint64_t sc  = cur[base + WPR];
                    uint64_t nw  = xw ? cur[base - WPR - 1] : 0;
                    uint64_t ne  = xe ? cur[base - WPR + 1] : 0;
                    uint64_t sw  = xw ? cur[base + WPR - 1] : 0;
                    uint64_t se  = xe ? cur[base + WPR + 1] : 0;
                    uint64_t del = zs_del(cc, nc, sc, cw, ce, nw, ne, sw, se, sub);
                    out = cc & ~del;
                    ch |= (del != 0);
                }
                nxt[base] = out;
                if (k == 0) nq0 = out; else nq1 = out;
            }
            // publish boundary rows of the NEW state (seq+1) from registers
            int par1 = (seq + 1) & 1;
            if (tid < WPR)        ST_RLX(&haloT[((myT << 1) | par1) * WPR + tid], nq0);        // q<8 -> lr==1
            if (tid >= 256 - WPR) ST_RLX(&haloB[((myT << 1) | par1) * WPR + (tid & 7)], nq1);  // q>=504 -> lr==RPS
            if (__any(ch) && (tid & 63) == 0) atomicOr(&chflag, 1);
            __syncthreads();     // drains all publishers' global stores + LDS writes
            if (tid == 0) ST_REL(&pubseq[myT], seq + 1);
            { uint64_t* t = cur; cur = nxt; nxt = t; }

            if (sub == 1) {
                if (tid == 0) {
                    int c = chflag;
                    int fidx = img * MAXIT + it;
                    if (c) __hip_atomic_fetch_or(&flag[fidx], 1, __ATOMIC_RELAXED, __HIP_MEMORY_SCOPE_AGENT);
                    int pos = __hip_atomic_fetch_add(&done[fidx], 1, __ATOMIC_ACQ_REL, __HIP_MEMORY_SCOPE_AGENT);
                    if (pos == S - 1) {
                        int fv = c ? 1 : LD_RLX(&flag[fidx]);
                        if (!fv) ST_REL(&conv[img], 1);   // full iteration, no strip changed
                    }
                    if (LD_RLX(&conv[img])) exitflag = 1;
                    chflag = 0;
                }
                __syncthreads();
            }
        }
        if (exitflag) break;
    }
finish:
    __syncthreads();
    for (int i = tid; i < QPS; i += 256) gimg[s * QPS + i] = cur[WPR + i];
}

// --- loss reduction: per-block partials (no atomics, no init), float4 loads, f64 accumulation
__global__ void __launch_bounds__(256) reduce_kernel(const float4* __restrict__ pred4, const float4* __restrict__ gt4,
                                                     const uint64_t* __restrict__ mask, double* __restrict__ part) {
    __shared__ double sh0[256];
    __shared__ double sh1[256];
    double a0 = 0.0, a1 = 0.0;
    const int N4 = TOTAL / 4;
    for (int i = blockIdx.x * blockDim.x + threadIdx.x; i < N4; i += RBLK * 256) {
        float4 p = pred4[i];
        float4 g = gt4[i];
        uint64_t mq = mask[i >> 4];
        int sh = (i & 15) * 4;
        double d, d2;
        d = (double)(p.x - g.x); d2 = d * d; a0 += d2; if ((mq >> (sh    )) & 1) a1 += d2;
        d = (double)(p.y - g.y); d2 = d * d; a0 += d2; if ((mq >> (sh + 1)) & 1) a1 += d2;
        d = (double)(p.z - g.z); d2 = d * d; a0 += d2; if ((mq >> (sh + 2)) & 1) a1 += d2;
        d = (double)(p.w - g.w); d2 = d * d; a0 += d2; if ((mq >> (sh + 3)) & 1) a1 += d2;
    }
    sh0[threadIdx.x] = a0;
    sh1[threadIdx.x] = a1;
    __syncthreads();
    for (int off = 128; off > 0; off >>= 1) {
        if (threadIdx.x < (unsigned)off) {
            sh0[threadIdx.x] += sh0[threadIdx.x + off];
            sh1[threadIdx.x] += sh1[threadIdx.x + off];
        }
        __syncthreads();
    }
    if (threadIdx.x == 0) {
        part[2 * blockIdx.x]     = sh0[0];
        part[2 * blockIdx.x + 1] = sh1[0];
    }
}

__global__ void __launch_bounds__(256) finalize_kernel(const double* __restrict__ part, float* __restrict__ out) {
    __shared__ double sh[256];
    double a = 0.0;
    for (int i = threadIdx.x; i < RBLK; i += 256) a += part[2 * i] + part[2 * i + 1];
    sh[threadIdx.x] = a;
    __syncthreads();
    for (int off = 128; off > 0; off >>= 1) {
        if (threadIdx.x < (unsigned)off) sh[threadIdx.x] += sh[threadIdx.x + off];
        __syncthreads();
    }
    if (threadIdx.x == 0) out[0] = (float)(0.5 * sh[0] / (double)TOTAL);
}

extern "C" void kernel_launch(void* const* d_in, const int* in_sizes, int n_in,
                              void* d_out, int out_size, void* d_ws, size_t ws_size,
                              hipStream_t stream) {
    const float* pred = (const float*)d_in[0];
    const float* gt   = (const float*)d_in[1];
    char* ws = (char*)d_ws;
    float*    tmp    = (float*)(ws + OFF_TMP);
    uint64_t* bufA   = (uint64_t*)(ws + OFF_PA);
    int*      flagA  = (int*)(ws + OFF_FLAG);
    int*      doneA  = (int*)(ws + OFF_DONE);
    int*      convA  = (int*)(ws + OFF_CONV);
    int*      pseqA  = (int*)(ws + OFF_PSEQ);
    uint64_t* haloT  = (uint64_t*)(ws + OFF_HALT);
    uint64_t* haloB  = (uint64_t*)(ws + OFF_HALB);
    double*   part   = (double*)(ws + OFF_PART);

    int nb = TOTAL / 256;
    blur_h<<<nb, 256, 0, stream>>>(gt, tmp, flagA);          // flagA == start of contiguous ctrl block
    blur_w_pack<<<nb, 256, 0, stream>>>(tmp, bufA);

    skel_strips<<<NIMG * S, 256, 0, stream>>>(bufA, flagA, doneA, convA, pseqA, haloT, haloB);

    reduce_kernel<<<RBLK, 256, 0, stream>>>((const float4*)pred, (const float4*)gt, bufA, part);
    finalize_kernel<<<1, 256, 0, stream>>>(part, (float*)d_out);
}